// Round 1
// baseline (315.446 us; speedup 1.0000x reference)
//
#include <hip/hip_runtime.h>
#include <math.h>

// SoftDTW, gamma=1, B=32, T=512. Cost depends only on row: d[b][i] = (x-y)^2.
// R[i,j] = d[i] + softmin(R[i-1,j], R[i,j-1], R[i-1,j-1]), result = mean_b R[T,T].
// Wavefront over anti-diagonals: 1023 serial steps, <=512 cells each.

#define TLEN 512
#define BATCH 32

__device__ __forceinline__ float softmin3(float a, float b, float c) {
    const float L2E = 1.44269504088896340736f;  // log2(e)
    const float LN2 = 0.69314718055994530942f;  // ln(2)
    float m = fminf(fminf(a, b), c);            // always finite for computed cells
    float s = exp2f((m - a) * L2E) + exp2f((m - b) * L2E) + exp2f((m - c) * L2E);
    return m - LN2 * log2f(s);
}

__global__ __launch_bounds__(TLEN) void softdtw_kernel(const float* __restrict__ x,
                                                       const float* __restrict__ y,
                                                       float* __restrict__ partial) {
    const int b = blockIdx.x;
    const int t = threadIdx.x;   // 0..511
    const int i = t + 1;         // DP row, 1..512
    const float BIG = 1e30f;     // finite stand-in for +inf (safe through min/exp path)

    // Rolling diagonal buffers: buffer for diagonal dd holds R[i, dd-i] at index i.
    __shared__ float bufA[TLEN + 1];
    __shared__ float bufB[TLEN + 1];
    __shared__ float bufC[TLEN + 1];

    float dx = x[b * TLEN + t] - y[b * TLEN + t];
    const float cost = dx * dx;  // cost of DP row i

    // Init: bufA = diagonal 0 (R[0,0]=0), bufB = diagonal 1 (R[0,1]=R[1,0]=inf).
    bufA[t] = BIG; bufB[t] = BIG; bufC[t] = BIG;
    if (t == 0) {
        bufA[TLEN] = BIG; bufB[TLEN] = BIG; bufC[TLEN] = BIG;
        bufA[0] = 0.0f;
    }
    __syncthreads();

    float* d2 = bufA;  // diagonal d-2
    float* d1 = bufB;  // diagonal d-1
    float* d0 = bufC;  // write target (holds dead diagonal d-3)

    float result = 0.0f;
    for (int d = 2; d <= 2 * TLEN; ++d) {
        const int j = d - i;
        if (j >= 1 && j <= TLEN) {
            float up   = d1[i - 1];  // R[i-1, j]
            float left = d1[i];      // R[i,   j-1]
            float dg   = d2[i - 1];  // R[i-1, j-1]
            float val = cost + softmin3(up, left, dg);
            d0[i] = val;
            if (d == 2 * TLEN) result = val;   // only i==T is active at d==2T
        } else if (j == 0) {
            d0[i] = BIG;             // column-0 boundary R[i,0] = inf
        }
        if (t == 0) d0[0] = BIG;     // row-0 boundary R[0,d] = inf (d>=2)
        __syncthreads();
        // rotate: write target for d+1 is the buffer holding d-2 (dead after this step)
        float* tmp = d2; d2 = d1; d1 = d0; d0 = tmp;
    }

    if (i == TLEN) partial[b] = result;
}

__global__ __launch_bounds__(64) void reduce_mean_kernel(const float* __restrict__ partial,
                                                         float* __restrict__ out) {
    const int t = threadIdx.x;   // one wave of 64
    float v = (t < BATCH) ? partial[t] : 0.0f;
    #pragma unroll
    for (int m = 32; m >= 1; m >>= 1) v += __shfl_xor(v, m, 64);
    if (t == 0) out[0] = v * (1.0f / BATCH);
}

extern "C" void kernel_launch(void* const* d_in, const int* in_sizes, int n_in,
                              void* d_out, int out_size, void* d_ws, size_t ws_size,
                              hipStream_t stream) {
    const float* x = (const float*)d_in[0];
    const float* y = (const float*)d_in[1];
    float* out = (float*)d_out;
    float* ws  = (float*)d_ws;   // 32 partial results

    softdtw_kernel<<<BATCH, TLEN, 0, stream>>>(x, y, ws);
    reduce_mean_kernel<<<1, 64, 0, stream>>>(ws, out);
}

// Round 3
// 188.829 us; speedup vs baseline: 1.6705x; 1.6705x over previous
//
#include <hip/hip_runtime.h>
#include <math.h>

// SoftDTW gamma=1, B=32, T=512, cost d[b][i] = (x-y)^2 depends only on row i.
// Exp-domain in DOUBLE: E[i,j] = exp(-R[i,j]) => E = w_i * (E_up + E_left + E_diag),
// w_i = exp(-d_i). Linear recurrence, no transcendentals, no renorm needed:
// useful cells have R <= R* + ~400 => E >= e^-745, inside f64 range; deeper
// cells underflow to 0 and contribute < e^-400 relative (negligible).
// One wave per batch: lane l owns rows 8l+1..8l+8 in registers; all lanes
// sweep anti-diagonal d (1023 serial steps); cross-lane boundary row passes
// via one __shfl_up per step. No LDS, no __syncthreads.

#define TLEN  512
#define BATCH 32
#define RPL   8      // rows per lane (512 / 64)

// One DP step. PA=true: activation phase (d<=513, active iff k<=actA);
// PA=false: deactivation phase (d>=514, active iff k>=actB).
template <bool PA>
__device__ __forceinline__ void dostep(double (&cur)[RPL], double (&prev)[RPL],
                                       double& nb1, double& nb2,
                                       const double (&w)[RPL],
                                       int actA, int actB, bool lane0) {
    double next[RPL];
    // bottom cell first so the boundary shuffle has the whole step to complete
    {
        constexpr int k = RPL - 1;
        double v = w[k] * (cur[k - 1] + cur[k] + prev[k - 1]);
        bool act = PA ? (k <= actA) : (k >= actB);
        next[k] = act ? v : 0.0;
    }
    double sh = __shfl_up(next[RPL - 1], 1, 64);
    #pragma unroll
    for (int k = 1; k < RPL - 1; ++k) {
        double v = w[k] * (cur[k - 1] + cur[k] + prev[k - 1]);
        bool act = PA ? (k <= actA) : (k >= actB);
        next[k] = act ? v : 0.0;
    }
    {
        double v = w[0] * (nb1 + cur[0] + nb2);  // nb1 = E[8l, j], nb2 = E[8l, j-1]
        bool act = PA ? (0 <= actA) : (0 >= actB);
        next[0] = act ? v : 0.0;
    }
    #pragma unroll
    for (int k = 0; k < RPL; ++k) { prev[k] = cur[k]; cur[k] = next[k]; }
    nb2 = nb1;
    nb1 = lane0 ? 0.0 : sh;   // row-0 boundary: E[0, j>=1] = 0
}

__global__ __launch_bounds__(64) void softdtw_kernel(const float* __restrict__ x,
                                                     const float* __restrict__ y,
                                                     float* __restrict__ partial) {
    const int b = blockIdx.x;
    const int l = threadIdx.x;           // 0..63
    const bool lane0 = (l == 0);

    double w[RPL];
    #pragma unroll
    for (int k = 0; k < RPL; ++k) {
        double dx = (double)x[b * TLEN + RPL * l + k] - (double)y[b * TLEN + RPL * l + k];
        w[k] = exp(-dx * dx);
    }

    double cur[RPL], prev[RPL];
    #pragma unroll
    for (int k = 0; k < RPL; ++k) { cur[k] = 0.0; prev[k] = 0.0; }
    double nb1 = 0.0;                    // E[8l, j]   on diag d-1
    double nb2 = lane0 ? 1.0 : 0.0;      // E[8l, j-1] on diag d-2; E[0,0] = 1
    int actA = -RPL * l;                 // = d-2-8l at d=2 (active: k <= actA, signed)

    // Phase A: d = 2..513 (rows activate; j <= 512 automatic)
    for (int d = 2; d <= TLEN + 1; ++d) {
        dostep<true>(cur, prev, nb1, nb2, w, actA, 0, lane0);
        ++actA;
    }
    // Phase B: d = 514..1024 (rows deactivate; j >= 1 automatic)
    int actB = actA - (TLEN - 1);        // = d-513-8l at d=514 (active: k >= actB)
    for (int d = TLEN + 2; d <= 2 * TLEN; ++d) {
        dostep<false>(cur, prev, nb1, nb2, w, 0, actB, lane0);
        ++actB;
    }

    // E[512,512] lives in cur[7] of lane 63.
    if (l == 63) partial[b] = (float)(-log(cur[RPL - 1]));
}

__global__ __launch_bounds__(64) void reduce_mean_kernel(const float* __restrict__ partial,
                                                         float* __restrict__ out) {
    const int t = threadIdx.x;
    float v = (t < BATCH) ? partial[t] : 0.0f;
    #pragma unroll
    for (int m = 32; m >= 1; m >>= 1) v += __shfl_xor(v, m, 64);
    if (t == 0) out[0] = v * (1.0f / BATCH);
}

extern "C" void kernel_launch(void* const* d_in, const int* in_sizes, int n_in,
                              void* d_out, int out_size, void* d_ws, size_t ws_size,
                              hipStream_t stream) {
    const float* x = (const float*)d_in[0];
    const float* y = (const float*)d_in[1];
    float* out = (float*)d_out;
    float* ws  = (float*)d_ws;

    softdtw_kernel<<<BATCH, 64, 0, stream>>>(x, y, ws);
    reduce_mean_kernel<<<1, 64, 0, stream>>>(ws, out);
}

// Round 4
// 119.212 us; speedup vs baseline: 2.6461x; 1.5840x over previous
//
#include <hip/hip_runtime.h>
#include <math.h>

// SoftDTW gamma=1, B=32, T=512, cost d[b][i] = (x-y)^2 depends only on row i.
// Exp-domain in f64: E[i,j] = exp(-R[i,j]) => E = w_i*(E_up + E_left + E_diag),
// w_i = exp(-d_i). 3 f64 flops/cell, no transcendentals, no renorm (f64 range
// covers all useful cells; deeper cells underflow harmlessly).
//
// One wave per batch; lane l owns rows 8l+1..8l+8 in registers; 1023 serial
// anti-diagonal steps; cross-lane boundary row via one f64 __shfl_up per step.
// No LDS, no barriers, no masking:
//  - pre-activation cells (j<=0) stay 0 by induction (only seed is lane0 nb2=1
//    = E[0,0] at d=2);
//  - post-active "extended" cells (j>512) are read only by other extended
//    cells (recurrence reads equal-or-lower column), cannot reach the valid
//    grid or the (512,512) readout, and cannot generate NaN (no subtraction,
//    w>0, nonneg operands).
// Step writes diag d into the diag d-2 buffer (dead) -> no register rotation.

#define TLEN  512
#define BATCH 32
#define RPL   8      // rows per lane (512 / 64)

// A = diag d-1, B = diag d-2 on entry; B <- diag d. Caller alternates roles.
__device__ __forceinline__ void dostep(double (&A)[RPL], double (&B)[RPL],
                                       double& nb1, double& nb2,
                                       const double (&w)[RPL], double lmask) {
    // bottom cell first so the boundary shuffle has the whole step to complete
    double bot = w[RPL - 1] * (A[RPL - 2] + A[RPL - 1] + B[RPL - 2]);
    double sh = __shfl_up(bot, 1, 64);
    #pragma unroll
    for (int k = RPL - 2; k >= 1; --k) {
        B[k] = w[k] * (A[k - 1] + A[k] + B[k - 1]);   // reads old B[k-1], ok (desc order)
    }
    B[RPL - 1] = bot;
    B[0] = w[0] * (nb1 + A[0] + nb2);  // nb1 = E[8l, j-? diag d-1], nb2 = diag d-2
    nb2 = nb1;
    nb1 = sh * lmask;                  // lane 0: row-0 boundary E[0, j>=1] = 0
}

__global__ __launch_bounds__(64) void softdtw_kernel(const float* __restrict__ x,
                                                     const float* __restrict__ y,
                                                     float* __restrict__ out) {
    const int b = blockIdx.x;
    const int l = threadIdx.x;                 // 0..63
    const double lmask = (l == 0) ? 0.0 : 1.0;

    double w[RPL];
    #pragma unroll
    for (int k = 0; k < RPL; ++k) {
        double dx = (double)x[b * TLEN + RPL * l + k] - (double)y[b * TLEN + RPL * l + k];
        w[k] = exp(-dx * dx);
    }

    double cur[RPL], prev[RPL];                // cur = diag 1 (all 0), prev = diag 0
    #pragma unroll
    for (int k = 0; k < RPL; ++k) { cur[k] = 0.0; prev[k] = 0.0; }
    double nb1 = 0.0;                          // E[8l, *] on diag d-1
    double nb2 = (l == 0) ? 1.0 : 0.0;         // E[0,0] = 1 seed

    // d = 2 (writes prev), then 511 double-steps covering d = 3..1024.
    dostep(cur, prev, nb1, nb2, w, lmask);
    for (int it = 0; it < (TLEN - 1); ++it) {
        dostep(prev, cur, nb1, nb2, w, lmask); // odd d  -> cur
        dostep(cur, prev, nb1, nb2, w, lmask); // even d -> prev
    }
    // d = 1024 landed in prev; E[512,512] = prev[7] of lane 63.
    if (l == 63) {
        float R = (float)(-log(prev[RPL - 1]));
        atomicAdd(out, R * (1.0f / BATCH));
    }
}

extern "C" void kernel_launch(void* const* d_in, const int* in_sizes, int n_in,
                              void* d_out, int out_size, void* d_ws, size_t ws_size,
                              hipStream_t stream) {
    const float* x = (const float*)d_in[0];
    const float* y = (const float*)d_in[1];
    float* out = (float*)d_out;

    hipMemsetAsync(out, 0, sizeof(float), stream);   // d_out is poisoned 0xAA
    softdtw_kernel<<<BATCH, 64, 0, stream>>>(x, y, out);
}